// Round 8
// baseline (144.459 us; speedup 1.0000x reference)
//
#include <hip/hip_runtime.h>
#include <cstdint>
#include <cstddef>

typedef __attribute__((ext_vector_type(4))) float f32x4;
typedef __attribute__((ext_vector_type(8))) short bf16x8;
typedef __attribute__((ext_vector_type(4))) short bf16x4;
typedef __attribute__((ext_vector_type(2))) short bf16x2;

#define DEVI static __device__ __forceinline__

DEVI short f2bf(float f){
  union { float f; uint32_t u; } v; v.f = f;
  uint32_t r = v.u + 0x7FFFu + ((v.u >> 16) & 1u);
  return (short)(r >> 16);
}
DEVI float bf2f(short h){
  union { uint32_t u; float f; } v; v.u = ((uint32_t)(uint16_t)h) << 16;
  return v.f;
}
DEVI float eluf(float x){ return x > 0.f ? x : (__expf(x) - 1.f); }
DEVI float sigm(float x){ return 1.f / (1.f + __expf(-x)); }

static constexpr int NPIX = 8 * 1024;   // B*S pixels

// ---- workspace layout (bytes) ----
static constexpr size_t SZ_W   = (size_t)983040 * 2;        // 3 x (w1 64K + w2 128K + wn 128K shorts), row-major
static constexpr size_t SZ_ACT = (size_t)NPIX * 256 * 2;
static constexpr size_t OFF_W   = 0;
static constexpr size_t OFF_TOK = OFF_W + SZ_W + 8*SZ_ACT;  // 3 x (B,512,1024) bf16 flat

// ---------------- weight fp32 -> bf16 (flat row-major) ----------------
__global__ void k_prep(const float* __restrict__ w1q, const float* __restrict__ w2q, const float* __restrict__ wnq,
                       const float* __restrict__ w1k, const float* __restrict__ w2k, const float* __restrict__ wnk,
                       const float* __restrict__ w1v, const float* __restrict__ w2v, const float* __restrict__ wnv,
                       short* __restrict__ dst)
{
  const float* s1[3] = {w1q, w1k, w1v};
  const float* s2[3] = {w2q, w2k, w2v};
  const float* s3[3] = {wnq, wnk, wnv};
  const int stride = gridDim.x * blockDim.x;
  for (int i = blockIdx.x * blockDim.x + threadIdx.x; i < 983040; i += stride){
    int br = i / 327680;
    int r  = i - br * 327680;
    float v;
    if (r < 65536)        v = s1[br][r];
    else if (r < 196608)  v = s2[br][r - 65536];
    else                  v = s3[br][r - 196608];
    dst[i] = f2bf(v);
  }
}

// ---------------- fused branch kernel, v6: W-IN-REGISTERS, M-split 16-row passes ----
// One block = 64 tokens x one branch z; 8 waves (512 threads).
// Each wave-pass preloads 16 W rows into registers (8 x bf16x8 = 32 VGPR)
// BEFORE its K-loop, then runs 32 MFMA against block-shared B tiles in LDS.
// A-side LDS traffic: ZERO. B reads: 4 ds_read_b128 per K-step feeding 4 MFMA,
// shared/broadcast across all 8 waves. Only 4 barriers per block.
// Row coverage: G1 (M=256): mbase = w*32 + p*16, p<2.
//               G2 (M=2x256): abase = p*128 + w*16, p<2 (a-rows; g-rows +256).
//               G3 (M=512):  mbase = p*128 + w*16, p<4.
// LDS: sEX (ex, later gr) 32 KB + sH1 (E-temp, later h1) 32 KB = 64 KB.
// __launch_bounds__(512,4) caps VGPR at 128 -> 2 blocks/CU = 16 waves/CU.
__global__ __launch_bounds__(512, 4)
void k_branch(const short* __restrict__ wsW,
              const float* __restrict__ query, const float* __restrict__ key,
              const float* __restrict__ b1q, const float* __restrict__ b1k, const float* __restrict__ b1v,
              const float* __restrict__ b2q, const float* __restrict__ b2k, const float* __restrict__ b2v,
              const float* __restrict__ bnq, const float* __restrict__ bnk, const float* __restrict__ bnv,
              short* __restrict__ tok)
{
  __shared__ short sEX[64*256];   // ex, later gr   (32 KB)
  __shared__ short sH1[64*256];   // E-temp [c][tok], later h1 [tok][m] (32 KB)

  const int z = blockIdx.y;
  const float* xin = (z == 0) ? query : key;
  const float* b1z = (z == 0) ? b1q : ((z == 1) ? b1k : b1v);
  const float* b2z = (z == 0) ? b2q : ((z == 1) ? b2k : b2v);
  const float* bnz = (z == 0) ? bnq : ((z == 1) ? bnk : bnv);
  const short* W1 = wsW + (size_t)z * 327680;
  const short* W2 = W1 + 65536;
  const short* Wn = W1 + 196608;
  short* tokz = tok + (size_t)z * NPIX * 512;

  const int tid = threadIdx.x, w = tid >> 6, hi = (tid >> 4) & 3, li = tid & 15;
  const int tile = blockIdx.x, b = tile >> 4, sp0 = (tile & 15) * 64;
  const float* xb = xin + (size_t)b * 256 * 1024;
  const int sw = (li & 7) << 3;   // column XOR swizzle for this lane's B reads

  // ---- phase E: x -> elu -> bf16, transposed into sEX[tok][c] (swizzled) ----
  #pragma unroll
  for (int i = 0; i < 8; i++){
    int idx = tid + i*512;                   // 4096 f32x4 units
    int c = idx >> 4, u = idx & 15;
    f32x4 v4 = *(const f32x4*)(xb + (size_t)c*1024 + sp0 + u*4);
    bf16x4 pk;
    #pragma unroll
    for (int r = 0; r < 4; r++) pk[r] = f2bf(eluf(v4[r]));
    *(bf16x4*)(sH1 + c*64 + u*4) = pk;       // temp [c][tok]
  }
  __syncthreads();
  #pragma unroll
  for (int i = 0; i < 4; i++){
    int idx = tid + i*512;                   // 2048 bf16x8 units
    int t = idx & 63, cb = idx >> 6;
    bf16x8 pk;
    #pragma unroll
    for (int j = 0; j < 8; j++) pk[j] = sH1[(cb*8 + j)*64 + t];
    *(bf16x8*)(sEX + t*256 + ((cb*8) ^ ((t & 7) << 3))) = pk;
  }
  __syncthreads();

  // ---- GEMM1: h1 = elu(W1 @ ex + b1) -> sH1[tok][m]; 2 passes x 16 rows ----
  #pragma unroll 1
  for (int p = 0; p < 2; p++){
    const int mbase = w*32 + p*16;
    bf16x8 A1[8];
    #pragma unroll
    for (int ks = 0; ks < 8; ks++)
      A1[ks] = *(const bf16x8*)(W1 + (size_t)(mbase + li)*256 + ks*32 + hi*8);
    f32x4 acc[4] = {};
    #pragma unroll
    for (int ks = 0; ks < 8; ks++){
      bf16x8 Bf[4];
      #pragma unroll
      for (int nt = 0; nt < 4; nt++)
        Bf[nt] = *(const bf16x8*)(sEX + (nt*16 + li)*256 + ((ks*32 + hi*8) ^ sw));
      #pragma unroll
      for (int nt = 0; nt < 4; nt++)
        acc[nt] = __builtin_amdgcn_mfma_f32_16x16x32_bf16(A1[ks], Bf[nt], acc[nt], 0, 0, 0);
    }
    const f32x4 bias = *(const f32x4*)(b1z + mbase + hi*4);
    #pragma unroll
    for (int nt = 0; nt < 4; nt++){
      bf16x4 pk;
      #pragma unroll
      for (int r = 0; r < 4; r++)
        pk[r] = f2bf(eluf(acc[nt][r] + bias[r]));
      *(bf16x4*)(sH1 + (nt*16 + li)*256 + ((mbase + hi*4) ^ sw)) = pk;
    }
  }
  __syncthreads();   // h1 complete; all ex reads done (gr may overwrite sEX)

  // ---- GEMM2: [a;g] = W2 @ h1 + b2 ; gr = x + a*sig(g) -> sEX; 2 pass-pairs ----
  #pragma unroll 1
  for (int p = 0; p < 2; p++){
    const int abase = p*128 + w*16;
    f32x4 aa[4] = {}, ag[4] = {};
    {
      bf16x8 Aa[8];
      #pragma unroll
      for (int ks = 0; ks < 8; ks++)
        Aa[ks] = *(const bf16x8*)(W2 + (size_t)(abase + li)*256 + ks*32 + hi*8);
      #pragma unroll
      for (int ks = 0; ks < 8; ks++){
        bf16x8 Bf[4];
        #pragma unroll
        for (int nt = 0; nt < 4; nt++)
          Bf[nt] = *(const bf16x8*)(sH1 + (nt*16 + li)*256 + ((ks*32 + hi*8) ^ sw));
        #pragma unroll
        for (int nt = 0; nt < 4; nt++)
          aa[nt] = __builtin_amdgcn_mfma_f32_16x16x32_bf16(Aa[ks], Bf[nt], aa[nt], 0, 0, 0);
      }
    }
    {
      bf16x8 Ag[8];
      #pragma unroll
      for (int ks = 0; ks < 8; ks++)
        Ag[ks] = *(const bf16x8*)(W2 + (size_t)(256 + abase + li)*256 + ks*32 + hi*8);
      #pragma unroll
      for (int ks = 0; ks < 8; ks++){
        bf16x8 Bf[4];
        #pragma unroll
        for (int nt = 0; nt < 4; nt++)
          Bf[nt] = *(const bf16x8*)(sH1 + (nt*16 + li)*256 + ((ks*32 + hi*8) ^ sw));
        #pragma unroll
        for (int nt = 0; nt < 4; nt++)
          ag[nt] = __builtin_amdgcn_mfma_f32_16x16x32_bf16(Ag[ks], Bf[nt], ag[nt], 0, 0, 0);
      }
    }
    const f32x4 ba = *(const f32x4*)(b2z + abase + hi*4);
    const f32x4 bg = *(const f32x4*)(b2z + 256 + abase + hi*4);
    #pragma unroll
    for (int nt = 0; nt < 4; nt++){
      bf16x4 pk;
      #pragma unroll
      for (int r = 0; r < 4; r++){
        float a  = aa[nt][r] + ba[r];
        float gg = ag[nt][r] + bg[r];
        float xv = xb[(size_t)(abase + hi*4 + r)*1024 + sp0 + nt*16 + li];
        pk[r] = f2bf(xv + a * sigm(gg));
      }
      *(bf16x4*)(sEX + (nt*16 + li)*256 + ((abase + hi*4) ^ sw)) = pk;
    }
  }
  __syncthreads();   // gr complete

  // ---- GEMM3: tok = Wn @ gr + bn -> global; 4 passes x 16 rows ----
  #pragma unroll 1
  for (int p = 0; p < 4; p++){
    const int mbase = p*128 + w*16;
    bf16x8 A3[8];
    #pragma unroll
    for (int ks = 0; ks < 8; ks++)
      A3[ks] = *(const bf16x8*)(Wn + (size_t)(mbase + li)*256 + ks*32 + hi*8);
    f32x4 acc[4] = {};
    #pragma unroll
    for (int ks = 0; ks < 8; ks++){
      bf16x8 Bf[4];
      #pragma unroll
      for (int nt = 0; nt < 4; nt++)
        Bf[nt] = *(const bf16x8*)(sEX + (nt*16 + li)*256 + ((ks*32 + hi*8) ^ sw));
      #pragma unroll
      for (int nt = 0; nt < 4; nt++)
        acc[nt] = __builtin_amdgcn_mfma_f32_16x16x32_bf16(A3[ks], Bf[nt], acc[nt], 0, 0, 0);
    }
    const f32x4 bias = *(const f32x4*)(bnz + mbase + hi*4);
    #pragma unroll
    for (int nt = 0; nt < 4; nt++)
      #pragma unroll
      for (int r = 0; r < 4; r++){
        int m = mbase + hi*4 + r;
        tokz[((size_t)b*512 + m)*1024 + sp0 + nt*16 + li] = f2bf(acc[nt][r] + bias[r]);
      }
  }
}

// ---------------- flash attention ----------------
// tok viewed as (B*1024 tokens, 512 feat) bf16; per (b, head): Q,K,V (1024 x 64).
// Strict causal (key < query), scale 1/sqrt(512), row 0 -> 0.
// Swapped QK^T: S^T = mfma(K, Q^T) so softmax state is lane-local.
// Grid = 1024 flat blocks; qt permuted so every stride-256 block family (one CU
// under XCD round-robin) has equal total work (perm stride-4 subsets sum to 30).
__global__ void k_attn(const short* __restrict__ tok, float* __restrict__ out)
{
  const short* qtok = tok;
  const short* ktok = tok + (size_t)NPIX * 512;
  const short* vtok = tok + (size_t)2 * NPIX * 512;
  const int flat = blockIdx.x;
  const int p = flat >> 6;
  const int g4 = p >> 2, r4 = p & 3;
  // perm = [15,14,13,12, 0,1,2,3, 11,10,9,8, 4,5,6,7]
  const int qt = (g4 == 0) ? (15 - r4) : (g4 == 1) ? r4 : (g4 == 2) ? (11 - r4) : (4 + r4);
  const int bh = flat & 63;
  const int b = bh >> 3, nh = bh & 7;
  const int tid = threadIdx.x, lane = tid & 63, w = tid >> 6, g = (tid >> 4) & 3, li = tid & 15;
  const int qrow = qt*64 + w*16 + li;       // this lane's query token
  __shared__ short Kl[64*64];
  __shared__ short Vt[64*64];               // V transposed: [d][k]
  __shared__ short Pl[4][1024];             // per-wave P [16 q][64 k]

  const short* qptr = qtok + ((size_t)(b*1024 + qrow))*512 + nh*64;
  bf16x8 qf0 = *(const bf16x8*)(qptr + g*8);
  bf16x8 qf1 = *(const bf16x8*)(qptr + 32 + g*8);

  f32x4 accO[4] = {};                       // O^T: 4 d-frags x (16d x 16q)
  float mrun = -1e30f, lrun = 0.f;
  const float scale = 0.04419417382415922f; // 1/sqrt(512)
  short* Pw = &Pl[w][0];

  for (int kt = 0; kt <= qt; kt++){
    const int kb = kt * 64;
    __syncthreads();
    #pragma unroll
    for (int it = 0; it < 2; it++){
      int i = tid + it*256;
      int kr = i >> 3, kc = i & 7;
      bf16x8 v = *(const bf16x8*)(ktok + ((size_t)(b*1024 + kb + kr))*512 + nh*64 + kc*8);
      *(bf16x8*)(Kl + ((kr*64 + kc*8) ^ ((kr & 7) << 3))) = v;
    }
    #pragma unroll
    for (int it = 0; it < 2; it++){
      int d0 = w*8 + it*32;                 // d uniform within wave -> conflict-free writes
      bf16x8 v = *(const bf16x8*)(vtok + ((size_t)(b*1024 + kb + lane))*512 + nh*64 + d0);
      #pragma unroll
      for (int j = 0; j < 8; j++){
        int d = d0 + j;
        Vt[(d*64 + lane) ^ ((d & 7) << 3)] = v[j];
      }
    }
    __syncthreads();

    // S^T frags: 4 x (16 keys x 16 q)
    float pv[16];
    float mt_ = -1e30f;
    const bool diag = (kt == qt);
    #pragma unroll
    for (int kf = 0; kf < 4; kf++){
      f32x4 sa = {};
      const int krow = kf*16 + li;
      bf16x8 ka  = *(const bf16x8*)(Kl + ((krow*64 + g*8) ^ ((krow & 7) << 3)));
      bf16x8 kbf = *(const bf16x8*)(Kl + ((krow*64 + 32 + g*8) ^ ((krow & 7) << 3)));
      sa = __builtin_amdgcn_mfma_f32_16x16x32_bf16(ka, qf0, sa, 0, 0, 0);
      sa = __builtin_amdgcn_mfma_f32_16x16x32_bf16(kbf, qf1, sa, 0, 0, 0);
      #pragma unroll
      for (int r = 0; r < 4; r++){
        const int keyg = kb + kf*16 + g*4 + r;
        float s = sa[r] * scale;
        const bool ok = (!diag) || (keyg < qrow);   // strict causal
        s = ok ? s : -1e30f;
        pv[kf*4 + r] = s;
        mt_ = fmaxf(mt_, s);
      }
    }
    mt_ = fmaxf(mt_, __shfl_xor(mt_, 16));
    mt_ = fmaxf(mt_, __shfl_xor(mt_, 32));
    const float mnew = fmaxf(mrun, mt_);
    const float alpha = __expf(mrun - mnew);
    short pr[16];
    float rs = 0.f;
    #pragma unroll
    for (int i2 = 0; i2 < 16; i2++){
      float p2 = (pv[i2] > -9e29f) ? __expf(pv[i2] - mnew) : 0.f;
      short pb = f2bf(p2);
      pr[i2] = pb;
      rs += bf2f(pb);            // denominator from rounded P (consistent with numerator)
    }
    rs += __shfl_xor(rs, 16);
    rs += __shfl_xor(rs, 32);
    lrun = lrun * alpha + rs;
    mrun = mnew;
    #pragma unroll
    for (int df = 0; df < 4; df++){
      accO[df][0] *= alpha; accO[df][1] *= alpha;
      accO[df][2] *= alpha; accO[df][3] *= alpha;
    }
    // P rows to per-wave LDS (b32 packed pairs; keys 4g+2rp consecutive)
    #pragma unroll
    for (int kf = 0; kf < 4; kf++){
      #pragma unroll
      for (int rp = 0; rp < 2; rp++){
        bf16x2 two;
        two[0] = pr[kf*4 + rp*2];
        two[1] = pr[kf*4 + rp*2 + 1];
        const int key = kf*16 + g*4 + rp*2;
        *(bf16x2*)(Pw + ((li*64 + key) ^ ((li & 7) << 3))) = two;
      }
    }
    // O^T += V^T @ P^T
    #pragma unroll
    for (int kc = 0; kc < 2; kc++){
      bf16x8 pf = *(const bf16x8*)(Pw + ((li*64 + kc*32 + g*8) ^ ((li & 7) << 3)));
      #pragma unroll
      for (int df = 0; df < 4; df++){
        const int dr = df*16 + li;
        bf16x8 vf = *(const bf16x8*)(Vt + ((dr*64 + kc*32 + g*8) ^ ((dr & 7) << 3)));
        accO[df] = __builtin_amdgcn_mfma_f32_16x16x32_bf16(vf, pf, accO[df], 0, 0, 0);
      }
    }
  }
  const float inv = (lrun > 0.f) ? (1.f / lrun) : 0.f;  // row 0: lrun==0 -> zeros (start_mask)
  #pragma unroll
  for (int df = 0; df < 4; df++){
    #pragma unroll
    for (int r = 0; r < 4; r++){
      const int d = df*16 + g*4 + r;
      out[((size_t)b*512 + nh*64 + d)*1024 + qrow] = accO[df][r] * inv;
    }
  }
}

extern "C" void kernel_launch(void* const* d_in, const int* in_sizes, int n_in,
                              void* d_out, int out_size, void* d_ws, size_t ws_size,
                              hipStream_t stream)
{
  (void)in_sizes; (void)n_in; (void)out_size; (void)ws_size;
  const float* query = (const float*)d_in[0];
  const float* key   = (const float*)d_in[1];
  const float* w1[3] = {(const float*)d_in[2],  (const float*)d_in[8],  (const float*)d_in[14]};
  const float* b1[3] = {(const float*)d_in[3],  (const float*)d_in[9],  (const float*)d_in[15]};
  const float* w2[3] = {(const float*)d_in[4],  (const float*)d_in[10], (const float*)d_in[16]};
  const float* b2[3] = {(const float*)d_in[5],  (const float*)d_in[11], (const float*)d_in[17]};
  const float* wn[3] = {(const float*)d_in[6],  (const float*)d_in[12], (const float*)d_in[18]};
  const float* bn[3] = {(const float*)d_in[7],  (const float*)d_in[13], (const float*)d_in[19]};

  char* ws = (char*)d_ws;
  short* wsW = (short*)(ws + OFF_W);
  short* tok = (short*)(ws + OFF_TOK);
  float* out = (float*)d_out;

  k_prep<<<dim3(960), dim3(256), 0, stream>>>(w1[0], w2[0], wn[0],
                                              w1[1], w2[1], wn[1],
                                              w1[2], w2[2], wn[2], wsW);
  k_branch<<<dim3(128, 3), dim3(512), 0, stream>>>(wsW, query, key,
                                                   b1[0], b1[1], b1[2],
                                                   b2[0], b2[1], b2[2],
                                                   bn[0], bn[1], bn[2], tok);
  k_attn<<<dim3(1024), dim3(256), 0, stream>>>(tok, out);
}

// Round 9
// 94.016 us; speedup vs baseline: 1.5365x; 1.5365x over previous
//
#include <hip/hip_runtime.h>
#include <cstdint>
#include <cstddef>

typedef __attribute__((ext_vector_type(4))) float f32x4;
typedef __attribute__((ext_vector_type(8))) short bf16x8;
typedef __attribute__((ext_vector_type(4))) short bf16x4;
typedef __attribute__((ext_vector_type(2))) short bf16x2;

#define DEVI static __device__ __forceinline__

DEVI short f2bf(float f){
  union { float f; uint32_t u; } v; v.f = f;
  uint32_t r = v.u + 0x7FFFu + ((v.u >> 16) & 1u);
  return (short)(r >> 16);
}
DEVI float bf2f(short h){
  union { uint32_t u; float f; } v; v.u = ((uint32_t)(uint16_t)h) << 16;
  return v.f;
}
DEVI float eluf(float x){ return x > 0.f ? x : (__expf(x) - 1.f); }
DEVI float sigm(float x){ return 1.f / (1.f + __expf(-x)); }

static constexpr int NPIX = 8 * 1024;   // B*S pixels

// ---- workspace layout (bytes) ----
static constexpr size_t SZ_W   = (size_t)983040 * 2;        // 3 x (w1 64K + w2 128K + wn 128K shorts), row-major
static constexpr size_t SZ_ACT = (size_t)NPIX * 256 * 2;
static constexpr size_t OFF_W   = 0;
static constexpr size_t OFF_TOK = OFF_W + SZ_W + 8*SZ_ACT;  // 3 x (B,512,1024) bf16 flat

// ---------------- weight fp32 -> bf16 (flat row-major) ----------------
__global__ void k_prep(const float* __restrict__ w1q, const float* __restrict__ w2q, const float* __restrict__ wnq,
                       const float* __restrict__ w1k, const float* __restrict__ w2k, const float* __restrict__ wnk,
                       const float* __restrict__ w1v, const float* __restrict__ w2v, const float* __restrict__ wnv,
                       short* __restrict__ dst)
{
  const float* s1[3] = {w1q, w1k, w1v};
  const float* s2[3] = {w2q, w2k, w2v};
  const float* s3[3] = {wnq, wnk, wnv};
  const int stride = gridDim.x * blockDim.x;
  for (int i = blockIdx.x * blockDim.x + threadIdx.x; i < 983040; i += stride){
    int br = i / 327680;
    int r  = i - br * 327680;
    float v;
    if (r < 65536)        v = s1[br][r];
    else if (r < 196608)  v = s2[br][r - 65536];
    else                  v = s3[br][r - 196608];
    dst[i] = f2bf(v);
  }
}

// ---------------- fused branch kernel, v7: W-in-registers, 4-wave blocks ----------------
// One block = 64 tokens x one branch z; 4 waves (256 threads).
// Each wave-pass preloads its W rows into registers (bf16x8 arrays, fully
// unrolled -> registers) BEFORE the K-loop, then MFMAs against block-shared
// B tiles in LDS (reads:MFMA = 0.5 with mt=2). A-side LDS traffic: zero.
// Only 4 barriers per block.
//   G1: p<2 passes, rows mbase = p*128 + w*32 (mt=2)
//   G2: p<4 passes, a-rows abase = p*64 + w*16 and g-rows 256+abase (both preloaded)
//   G3: p<4 passes, rows mbase = p*128 + w*32 (mt=2)
// LDS: sEX (ex->gr) 32 KB + sH1 (E-temp->h1) 32 KB = 64 KB -> 2 blocks/CU.
// __launch_bounds__(256,2): VGPR cap 256 (expect ~150-190 live, NO spills --
// R8's (512,4) capped at 64 arch VGPRs and spilled everything to scratch).
__global__ __launch_bounds__(256, 2)
void k_branch(const short* __restrict__ wsW,
              const float* __restrict__ query, const float* __restrict__ key,
              const float* __restrict__ b1q, const float* __restrict__ b1k, const float* __restrict__ b1v,
              const float* __restrict__ b2q, const float* __restrict__ b2k, const float* __restrict__ b2v,
              const float* __restrict__ bnq, const float* __restrict__ bnk, const float* __restrict__ bnv,
              short* __restrict__ tok)
{
  __shared__ short sEX[64*256];   // ex, later gr   (32 KB)
  __shared__ short sH1[64*256];   // E-temp [c][tok], later h1 [tok][m] (32 KB)

  const int z = blockIdx.y;
  const float* xin = (z == 0) ? query : key;
  const float* b1z = (z == 0) ? b1q : ((z == 1) ? b1k : b1v);
  const float* b2z = (z == 0) ? b2q : ((z == 1) ? b2k : b2v);
  const float* bnz = (z == 0) ? bnq : ((z == 1) ? bnk : bnv);
  const short* W1 = wsW + (size_t)z * 327680;
  const short* W2 = W1 + 65536;
  const short* Wn = W1 + 196608;
  short* tokz = tok + (size_t)z * NPIX * 512;

  const int tid = threadIdx.x, w = tid >> 6, hi = (tid >> 4) & 3, li = tid & 15;
  const int tile = blockIdx.x, b = tile >> 4, sp0 = (tile & 15) * 64;
  const float* xb = xin + (size_t)b * 256 * 1024;
  const int sw = (li & 7) << 3;   // column XOR swizzle for this lane's B reads/writes

  // ---- phase E: x -> elu -> bf16, transposed into sEX[tok][c] (swizzled) ----
  #pragma unroll
  for (int i = 0; i < 16; i++){
    int idx = tid + i*256;                   // 4096 f32x4 units
    int c = idx >> 4, u = idx & 15;
    f32x4 v4 = *(const f32x4*)(xb + (size_t)c*1024 + sp0 + u*4);
    bf16x4 pk;
    #pragma unroll
    for (int r = 0; r < 4; r++) pk[r] = f2bf(eluf(v4[r]));
    *(bf16x4*)(sH1 + c*64 + u*4) = pk;       // temp [c][tok]
  }
  __syncthreads();
  #pragma unroll
  for (int i = 0; i < 8; i++){
    int idx = tid + i*256;                   // 2048 bf16x8 units
    int t = idx & 63, cb = idx >> 6;
    bf16x8 pk;
    #pragma unroll
    for (int j = 0; j < 8; j++) pk[j] = sH1[(cb*8 + j)*64 + t];
    *(bf16x8*)(sEX + t*256 + ((cb*8) ^ ((t & 7) << 3))) = pk;
  }
  __syncthreads();

  // ---- GEMM1: h1 = elu(W1 @ ex + b1) -> sH1[tok][m]; 2 passes x 32 rows/wave ----
  #pragma unroll 1
  for (int p = 0; p < 2; p++){
    const int mbase = p*128 + w*32;
    bf16x8 A[2][8];
    #pragma unroll
    for (int mt = 0; mt < 2; mt++)
      #pragma unroll
      for (int ks = 0; ks < 8; ks++)
        A[mt][ks] = *(const bf16x8*)(W1 + (size_t)(mbase + mt*16 + li)*256 + ks*32 + hi*8);
    f32x4 acc[2][4] = {};
    #pragma unroll
    for (int ks = 0; ks < 8; ks++){
      bf16x8 Bf[4];
      #pragma unroll
      for (int nt = 0; nt < 4; nt++)
        Bf[nt] = *(const bf16x8*)(sEX + (nt*16 + li)*256 + ((ks*32 + hi*8) ^ sw));
      #pragma unroll
      for (int mt = 0; mt < 2; mt++)
        #pragma unroll
        for (int nt = 0; nt < 4; nt++)
          acc[mt][nt] = __builtin_amdgcn_mfma_f32_16x16x32_bf16(A[mt][ks], Bf[nt], acc[mt][nt], 0, 0, 0);
    }
    #pragma unroll
    for (int mt = 0; mt < 2; mt++){
      const f32x4 bias = *(const f32x4*)(b1z + mbase + mt*16 + hi*4);
      #pragma unroll
      for (int nt = 0; nt < 4; nt++){
        bf16x4 pk;
        #pragma unroll
        for (int r = 0; r < 4; r++)
          pk[r] = f2bf(eluf(acc[mt][nt][r] + bias[r]));
        *(bf16x4*)(sH1 + (nt*16 + li)*256 + ((mbase + mt*16 + hi*4) ^ sw)) = pk;
      }
    }
  }
  __syncthreads();   // h1 complete; ex fully consumed (gr may overwrite sEX)

  // ---- GEMM2: [a;g] = W2 @ h1 + b2 ; gr = x + a*sig(g) -> sEX; 4 passes x 16 rows ----
  #pragma unroll 1
  for (int p = 0; p < 4; p++){
    const int abase = p*64 + w*16;
    bf16x8 Aa[8], Ag[8];
    #pragma unroll
    for (int ks = 0; ks < 8; ks++){
      Aa[ks] = *(const bf16x8*)(W2 + (size_t)(abase + li)*256 + ks*32 + hi*8);
      Ag[ks] = *(const bf16x8*)(W2 + (size_t)(256 + abase + li)*256 + ks*32 + hi*8);
    }
    f32x4 aa[4] = {}, ag[4] = {};
    #pragma unroll
    for (int ks = 0; ks < 8; ks++){
      bf16x8 Bf[4];
      #pragma unroll
      for (int nt = 0; nt < 4; nt++)
        Bf[nt] = *(const bf16x8*)(sH1 + (nt*16 + li)*256 + ((ks*32 + hi*8) ^ sw));
      #pragma unroll
      for (int nt = 0; nt < 4; nt++){
        aa[nt] = __builtin_amdgcn_mfma_f32_16x16x32_bf16(Aa[ks], Bf[nt], aa[nt], 0, 0, 0);
        ag[nt] = __builtin_amdgcn_mfma_f32_16x16x32_bf16(Ag[ks], Bf[nt], ag[nt], 0, 0, 0);
      }
    }
    const f32x4 ba = *(const f32x4*)(b2z + abase + hi*4);
    const f32x4 bg = *(const f32x4*)(b2z + 256 + abase + hi*4);
    #pragma unroll
    for (int nt = 0; nt < 4; nt++){
      bf16x4 pk;
      #pragma unroll
      for (int r = 0; r < 4; r++){
        float a  = aa[nt][r] + ba[r];
        float gg = ag[nt][r] + bg[r];
        float xv = xb[(size_t)(abase + hi*4 + r)*1024 + sp0 + nt*16 + li];
        pk[r] = f2bf(xv + a * sigm(gg));
      }
      *(bf16x4*)(sEX + (nt*16 + li)*256 + ((abase + hi*4) ^ sw)) = pk;
    }
  }
  __syncthreads();   // gr complete

  // ---- GEMM3: tok = Wn @ gr + bn -> global; 4 passes x 32 rows/wave ----
  #pragma unroll 1
  for (int p = 0; p < 4; p++){
    const int mbase = p*128 + w*32;
    bf16x8 A[2][8];
    #pragma unroll
    for (int mt = 0; mt < 2; mt++)
      #pragma unroll
      for (int ks = 0; ks < 8; ks++)
        A[mt][ks] = *(const bf16x8*)(Wn + (size_t)(mbase + mt*16 + li)*256 + ks*32 + hi*8);
    f32x4 acc[2][4] = {};
    #pragma unroll
    for (int ks = 0; ks < 8; ks++){
      bf16x8 Bf[4];
      #pragma unroll
      for (int nt = 0; nt < 4; nt++)
        Bf[nt] = *(const bf16x8*)(sEX + (nt*16 + li)*256 + ((ks*32 + hi*8) ^ sw));
      #pragma unroll
      for (int mt = 0; mt < 2; mt++)
        #pragma unroll
        for (int nt = 0; nt < 4; nt++)
          acc[mt][nt] = __builtin_amdgcn_mfma_f32_16x16x32_bf16(A[mt][ks], Bf[nt], acc[mt][nt], 0, 0, 0);
    }
    #pragma unroll
    for (int mt = 0; mt < 2; mt++){
      const f32x4 bias = *(const f32x4*)(bnz + mbase + mt*16 + hi*4);
      #pragma unroll
      for (int nt = 0; nt < 4; nt++)
        #pragma unroll
        for (int r = 0; r < 4; r++){
          int m = mbase + mt*16 + hi*4 + r;
          tokz[((size_t)b*512 + m)*1024 + sp0 + nt*16 + li] = f2bf(acc[mt][nt][r] + bias[r]);
        }
    }
  }
}

// ---------------- flash attention ----------------
// tok viewed as (B*1024 tokens, 512 feat) bf16; per (b, head): Q,K,V (1024 x 64).
// Strict causal (key < query), scale 1/sqrt(512), row 0 -> 0.
// Swapped QK^T: S^T = mfma(K, Q^T) so softmax state is lane-local.
// Grid = 1024 flat blocks; qt permuted so every stride-256 block family (one CU
// under XCD round-robin) has equal total work (perm stride-4 subsets sum to 30).
__global__ void k_attn(const short* __restrict__ tok, float* __restrict__ out)
{
  const short* qtok = tok;
  const short* ktok = tok + (size_t)NPIX * 512;
  const short* vtok = tok + (size_t)2 * NPIX * 512;
  const int flat = blockIdx.x;
  const int p = flat >> 6;
  const int g4 = p >> 2, r4 = p & 3;
  // perm = [15,14,13,12, 0,1,2,3, 11,10,9,8, 4,5,6,7]
  const int qt = (g4 == 0) ? (15 - r4) : (g4 == 1) ? r4 : (g4 == 2) ? (11 - r4) : (4 + r4);
  const int bh = flat & 63;
  const int b = bh >> 3, nh = bh & 7;
  const int tid = threadIdx.x, lane = tid & 63, w = tid >> 6, g = (tid >> 4) & 3, li = tid & 15;
  const int qrow = qt*64 + w*16 + li;       // this lane's query token
  __shared__ short Kl[64*64];
  __shared__ short Vt[64*64];               // V transposed: [d][k]
  __shared__ short Pl[4][1024];             // per-wave P [16 q][64 k]

  const short* qptr = qtok + ((size_t)(b*1024 + qrow))*512 + nh*64;
  bf16x8 qf0 = *(const bf16x8*)(qptr + g*8);
  bf16x8 qf1 = *(const bf16x8*)(qptr + 32 + g*8);

  f32x4 accO[4] = {};                       // O^T: 4 d-frags x (16d x 16q)
  float mrun = -1e30f, lrun = 0.f;
  const float scale = 0.04419417382415922f; // 1/sqrt(512)
  short* Pw = &Pl[w][0];

  for (int kt = 0; kt <= qt; kt++){
    const int kb = kt * 64;
    __syncthreads();
    #pragma unroll
    for (int it = 0; it < 2; it++){
      int i = tid + it*256;
      int kr = i >> 3, kc = i & 7;
      bf16x8 v = *(const bf16x8*)(ktok + ((size_t)(b*1024 + kb + kr))*512 + nh*64 + kc*8);
      *(bf16x8*)(Kl + ((kr*64 + kc*8) ^ ((kr & 7) << 3))) = v;
    }
    #pragma unroll
    for (int it = 0; it < 2; it++){
      int d0 = w*8 + it*32;                 // d uniform within wave -> conflict-free writes
      bf16x8 v = *(const bf16x8*)(vtok + ((size_t)(b*1024 + kb + lane))*512 + nh*64 + d0);
      #pragma unroll
      for (int j = 0; j < 8; j++){
        int d = d0 + j;
        Vt[(d*64 + lane) ^ ((d & 7) << 3)] = v[j];
      }
    }
    __syncthreads();

    // S^T frags: 4 x (16 keys x 16 q)
    float pv[16];
    float mt_ = -1e30f;
    const bool diag = (kt == qt);
    #pragma unroll
    for (int kf = 0; kf < 4; kf++){
      f32x4 sa = {};
      const int krow = kf*16 + li;
      bf16x8 ka  = *(const bf16x8*)(Kl + ((krow*64 + g*8) ^ ((krow & 7) << 3)));
      bf16x8 kbf = *(const bf16x8*)(Kl + ((krow*64 + 32 + g*8) ^ ((krow & 7) << 3)));
      sa = __builtin_amdgcn_mfma_f32_16x16x32_bf16(ka, qf0, sa, 0, 0, 0);
      sa = __builtin_amdgcn_mfma_f32_16x16x32_bf16(kbf, qf1, sa, 0, 0, 0);
      #pragma unroll
      for (int r = 0; r < 4; r++){
        const int keyg = kb + kf*16 + g*4 + r;
        float s = sa[r] * scale;
        const bool ok = (!diag) || (keyg < qrow);   // strict causal
        s = ok ? s : -1e30f;
        pv[kf*4 + r] = s;
        mt_ = fmaxf(mt_, s);
      }
    }
    mt_ = fmaxf(mt_, __shfl_xor(mt_, 16));
    mt_ = fmaxf(mt_, __shfl_xor(mt_, 32));
    const float mnew = fmaxf(mrun, mt_);
    const float alpha = __expf(mrun - mnew);
    short pr[16];
    float rs = 0.f;
    #pragma unroll
    for (int i2 = 0; i2 < 16; i2++){
      float p2 = (pv[i2] > -9e29f) ? __expf(pv[i2] - mnew) : 0.f;
      short pb = f2bf(p2);
      pr[i2] = pb;
      rs += bf2f(pb);            // denominator from rounded P (consistent with numerator)
    }
    rs += __shfl_xor(rs, 16);
    rs += __shfl_xor(rs, 32);
    lrun = lrun * alpha + rs;
    mrun = mnew;
    #pragma unroll
    for (int df = 0; df < 4; df++){
      accO[df][0] *= alpha; accO[df][1] *= alpha;
      accO[df][2] *= alpha; accO[df][3] *= alpha;
    }
    // P rows to per-wave LDS (b32 packed pairs; keys 4g+2rp consecutive)
    #pragma unroll
    for (int kf = 0; kf < 4; kf++){
      #pragma unroll
      for (int rp = 0; rp < 2; rp++){
        bf16x2 two;
        two[0] = pr[kf*4 + rp*2];
        two[1] = pr[kf*4 + rp*2 + 1];
        const int key = kf*16 + g*4 + rp*2;
        *(bf16x2*)(Pw + ((li*64 + key) ^ ((li & 7) << 3))) = two;
      }
    }
    // O^T += V^T @ P^T
    #pragma unroll
    for (int kc = 0; kc < 2; kc++){
      bf16x8 pf = *(const bf16x8*)(Pw + ((li*64 + kc*32 + g*8) ^ ((li & 7) << 3)));
      #pragma unroll
      for (int df = 0; df < 4; df++){
        const int dr = df*16 + li;
        bf16x8 vf = *(const bf16x8*)(Vt + ((dr*64 + kc*32 + g*8) ^ ((dr & 7) << 3)));
        accO[df] = __builtin_amdgcn_mfma_f32_16x16x32_bf16(vf, pf, accO[df], 0, 0, 0);
      }
    }
  }
  const float inv = (lrun > 0.f) ? (1.f / lrun) : 0.f;  // row 0: lrun==0 -> zeros (start_mask)
  #pragma unroll
  for (int df = 0; df < 4; df++){
    #pragma unroll
    for (int r = 0; r < 4; r++){
      const int d = df*16 + g*4 + r;
      out[((size_t)b*512 + nh*64 + d)*1024 + qrow] = accO[df][r] * inv;
    }
  }
}

extern "C" void kernel_launch(void* const* d_in, const int* in_sizes, int n_in,
                              void* d_out, int out_size, void* d_ws, size_t ws_size,
                              hipStream_t stream)
{
  (void)in_sizes; (void)n_in; (void)out_size; (void)ws_size;
  const float* query = (const float*)d_in[0];
  const float* key   = (const float*)d_in[1];
  const float* w1[3] = {(const float*)d_in[2],  (const float*)d_in[8],  (const float*)d_in[14]};
  const float* b1[3] = {(const float*)d_in[3],  (const float*)d_in[9],  (const float*)d_in[15]};
  const float* w2[3] = {(const float*)d_in[4],  (const float*)d_in[10], (const float*)d_in[16]};
  const float* b2[3] = {(const float*)d_in[5],  (const float*)d_in[11], (const float*)d_in[17]};
  const float* wn[3] = {(const float*)d_in[6],  (const float*)d_in[12], (const float*)d_in[18]};
  const float* bn[3] = {(const float*)d_in[7],  (const float*)d_in[13], (const float*)d_in[19]};

  char* ws = (char*)d_ws;
  short* wsW = (short*)(ws + OFF_W);
  short* tok = (short*)(ws + OFF_TOK);
  float* out = (float*)d_out;

  k_prep<<<dim3(960), dim3(256), 0, stream>>>(w1[0], w2[0], wn[0],
                                              w1[1], w2[1], wn[1],
                                              w1[2], w2[2], wn[2], wsW);
  k_branch<<<dim3(128, 3), dim3(256), 0, stream>>>(wsW, query, key,
                                                   b1[0], b1[1], b1[2],
                                                   b2[0], b2[1], b2[2],
                                                   bn[0], bn[1], bn[2], tok);
  k_attn<<<dim3(1024), dim3(256), 0, stream>>>(tok, out);
}